// Round 13
// baseline (1491.176 us; speedup 1.0000x reference)
//
#include <hip/hip_runtime.h>
#include <math.h>

#define SS   96
#define TM   96
#define BB   8
#define VV   32000
#define EE   256
#define HH   512
#define NTOK (SS + TM)     // 192
#define G4   (4 * HH)      // 2048
#define NEGF (-1e30f)
#define LBLK 16            // k_lstm blocks (64 waves)

// k_prep unit counts
#define NXIH  768                      // 96 token-tiles x 8 row-blocks
#define NCVTW 512                      // Whh: 1,048,576 f / 2048
#define NCVTR 8000                     // Wread: 16,384,000 f / 2048
#define NPREP (NXIH + NCVTW + NCVTR)   // 9280

typedef __attribute__((ext_vector_type(8))) short short8;
typedef __attribute__((ext_vector_type(4))) float f32x4;
typedef __attribute__((ext_vector_type(4))) unsigned uint32x4;
typedef unsigned long long u64;

// ---- workspace layout (float offsets) ----
#define XIH_OFF   ((size_t)0)
#define XIH_SZ    ((size_t)NTOK * BB * G4)       // 3,145,728 f
#define HALL_OFF  (XIH_OFF + XIH_SZ)
#define HALL_SZ   ((size_t)NTOK * BB * HH)       // 786,432 f
#define Q_OFF     (HALL_OFF + HALL_SZ)
#define Q_SZ      ((size_t)TM * BB * HH)         // 393,216 f
#define PPTR_OFF  (Q_OFF + Q_SZ)
#define ASENT_OFF (PPTR_OFF + (size_t)(TM * BB))
#define SSUM_OFF  (ASENT_OFF + (size_t)(TM * BB))
#define LSTAR_OFF (SSUM_OFF + (size_t)(TM * BB))
#define FLAG_OFF  (LSTAR_OFF + (size_t)(TM * BB))   // 16 lines x 16 u32; line l = block l's 4 wave flags
#define HBF_OFF   (FLAG_OFF + (size_t)1024)
#define HBF_SZF   ((size_t)2 * BB * HH / 2)         // 4,096 f (2 x 8 x 512 bf16)
#define WHHBF_OFF (HBF_OFF + HBF_SZF)
#define WHHBF_SZF ((size_t)G4 * HH / 2)             // 524,288 f
#define ABF_OFF   (WHHBF_OFF + WHHBF_SZF)
#define ABF_SZF   ((size_t)(TM * BB) * HH / 2)      // 196,608 f
#define WBF_OFF   (ABF_OFF + ABF_SZF)
#define WBF_SZF   ((size_t)VV * HH / 2)             // 8,192,000 f
#define NEED_F    (WBF_OFF + WBF_SZF)

__device__ __forceinline__ float sigf(float x) { return 1.f / (1.f + __expf(-x)); }

__device__ __forceinline__ unsigned short f2bf(float x) {
    unsigned bits = __float_as_uint(x);
    bits += 0x7FFFu + ((bits >> 16) & 1u);   // RNE
    return (unsigned short)(bits >> 16);
}

// ============ Kernel 1: prep = xih tiles + Whh cvt + Wread cvt (one launch) ============
__global__ void __launch_bounds__(256) k_prep(const int* __restrict__ src,
                                              const int* __restrict__ tgt,
                                              const float* __restrict__ emb,
                                              const float* __restrict__ Wih,
                                              const float* __restrict__ bih,
                                              const float* __restrict__ bhh,
                                              const float* __restrict__ Whh,
                                              const float* __restrict__ Wread,
                                              float* __restrict__ xih,
                                              unsigned short* __restrict__ whhbf,
                                              unsigned short* __restrict__ wbf) {
    __shared__ float xs[16 * EE];   // 16 KB
    const int bid = blockIdx.x;
    const int tid = threadIdx.x;

    if (bid < NXIH) {
        const int tok0 = (bid >> 3) * 16;
        const int row0 = (bid & 7) * 256;
        for (int e = tid; e < 16 * EE; e += 256) {
            int tk = e >> 8, k = e & 255;
            int tau = tok0 + tk;
            int idx = (tau < SS * BB) ? src[tau] : tgt[tau - SS * BB];
            xs[tk * EE + k] = (idx == 0) ? 0.f : emb[(size_t)idx * EE + k];
        }
        __syncthreads();

        const int row = row0 + tid;
        const float bias = bih[row] + bhh[row];
        float acc[16];
#pragma unroll
        for (int r = 0; r < 16; ++r) acc[r] = bias;
        const float4* w4 = (const float4*)(Wih + (size_t)row * EE);
        for (int k4 = 0; k4 < EE / 4; ++k4) {
            float4 w = w4[k4];
#pragma unroll
            for (int r = 0; r < 16; ++r) {
                float4 x = *((const float4*)&xs[r * EE + k4 * 4]);
                acc[r] += w.x * x.x + w.y * x.y + w.z * x.z + w.w * x.w;
            }
        }
#pragma unroll
        for (int r = 0; r < 16; ++r)
            xih[(size_t)(tok0 + r) * G4 + row] = acc[r];
        return;
    }

    const float* srcp;
    unsigned short* dstp;
    size_t base;
    if (bid < NXIH + NCVTW) { srcp = Whh;   dstp = whhbf; base = (size_t)(bid - NXIH) * 2048; }
    else                    { srcp = Wread; dstp = wbf;   base = (size_t)(bid - NXIH - NCVTW) * 2048; }
    base += (size_t)tid * 8;
    float4 f0 = *(const float4*)(srcp + base);
    float4 f1 = *(const float4*)(srcp + base + 4);
    uint4 o;
    o.x = (unsigned)f2bf(f0.x) | ((unsigned)f2bf(f0.y) << 16);
    o.y = (unsigned)f2bf(f0.z) | ((unsigned)f2bf(f0.w) << 16);
    o.z = (unsigned)f2bf(f1.x) | ((unsigned)f2bf(f1.y) << 16);
    o.w = (unsigned)f2bf(f1.z) | ((unsigned)f2bf(f1.w) << 16);
    *(uint4*)(dstp + base) = o;
}

// ============ Kernel 2: LSTM scan — LDS weights + PACKED per-wave flags ============
// 16 blocks x 256 thr (64 waves). Wave wv: gate-rows I0 = bx*32 + wv*8 (x4 gates);
// each wave publishes a complete h slice -> per-wave readiness, NO in-loop barrier.
// Flags packed: line l (64B) holds block l's 4 wave-flag dwords. Producer wave:
// wave-level vmcnt(0) drain (covers all its lanes' publishes) -> store OWN dword
// (no sibling wait). Consumer: lanes l<16 load dwordx4 of line l -> checks all 64
// wave flags with r11-level poll traffic (16 lines). All cross-block traffic
// device-coherent (sc0 sc1). Parity-2 dbuf safe by the r3/r11 induction.
__global__ void __launch_bounds__(256, 1) k_lstm(const float* __restrict__ xih,
                                                 const unsigned short* __restrict__ whhbf,
                                                 float* __restrict__ hall,
                                                 unsigned short* __restrict__ hbf,
                                                 unsigned short* __restrict__ abf,
                                                 unsigned* __restrict__ flags) {
    extern __shared__ short lA[];   // 131072 B
    const int tid = threadIdx.x;
    const int wv  = tid >> 6;
    const int l   = tid & 63;
    const int b16 = l & 15;          // MFMA col = batch (cols 8..15 don't-care)
    const int kg  = l >> 4;          // 0..3
    const int bb  = b16 & 7;
    const int bx  = blockIdx.x;
    const int I0  = bx * 32 + wv * 8;
    unsigned* myflag = flags + (size_t)bx * 16 + wv;   // dword wv of line bx

    // ---- stage A fragments into LDS (once; r9-verified layout) ----
    const int j = b16;
    const unsigned short* a0p = whhbf + ((size_t)((j >> 3) * HH + I0 + (j & 7))) * HH + kg * 8;
    const unsigned short* a1p = whhbf + ((size_t)((2 + (j >> 3)) * HH + I0 + (j & 7))) * HH + kg * 8;
    short* lA0 = lA + (((size_t)wv * 2 + 0) * 16 * 64 + l) * 8;
    short* lA1 = lA + (((size_t)wv * 2 + 1) * 16 * 64 + l) * 8;
#pragma unroll
    for (int ks = 0; ks < 16; ++ks) {
        *(short8*)(lA0 + ks * 512) = *(const short8*)(a0p + ks * 32);
        *(short8*)(lA1 + ks * 512) = *(const short8*)(a1p + ks * 32);
    }
    __syncthreads();   // LDS weights ready (only barrier in the kernel)

    const int xgate0 = (kg >> 1);        // 0:i 1:f
    const int xgate1 = 2 + (kg >> 1);    // 2:g 3:o
    const int xi     = I0 + (kg & 1) * 4;

    float c0[4] = {0.f, 0.f, 0.f, 0.f};
    union fragu { uint32x4 u4; short8 s; };

    for (int t = 0; t < NTOK; ++t) {
        // issue xih loads early (plain cached; resolve under the poll)
        const float* xb = xih + ((size_t)t * BB + bb) * G4;
        float4 x0 = *(const float4*)(xb + xgate0 * HH + xi);
        float4 x1 = *(const float4*)(xb + xgate1 * HH + xi);

        fragu Bf[16];
        if (t > 0) {
            // poll: lane l<16 loads line l (block l's 4 wave flags) in one dwordx4
            if (l < 16) {
                const unsigned* fp = flags + (size_t)l * 16;
                for (;;) {
                    uint32x4 fv;
                    asm volatile("global_load_dwordx4 %0, %1, off sc0 sc1\n\ts_waitcnt vmcnt(0)"
                                 : "=v"(fv) : "v"(fp) : "memory");
                    if (fv.x >= (unsigned)t && fv.y >= (unsigned)t &&
                        fv.z >= (unsigned)t && fv.w >= (unsigned)t) break;
                }
            }
            // batched B loads (h_{t-1}, parity (t-1)&1), one wait for all 16
            const unsigned short* hsrc =
                hbf + ((t - 1) & 1) * (BB * HH) + (size_t)bb * HH + kg * 8;
#pragma unroll
            for (int ks = 0; ks < 16; ++ks)
                asm volatile("global_load_dwordx4 %0, %1, off sc0 sc1"
                             : "=v"(Bf[ks].u4) : "v"(hsrc + ks * 32) : "memory");
            asm volatile("s_waitcnt vmcnt(0)" ::: "memory");
            __builtin_amdgcn_sched_barrier(0);
        }

        f32x4 acc0 = {x0.x, x0.y, x0.z, x0.w};
        f32x4 acc1 = {x1.x, x1.y, x1.z, x1.w};
        if (t > 0) {
#pragma unroll
            for (int ks = 0; ks < 16; ++ks) {
                short8 a0 = *(const short8*)(lA0 + ks * 512);
                short8 a1 = *(const short8*)(lA1 + ks * 512);
                acc0 = __builtin_amdgcn_mfma_f32_16x16x32_bf16(a0, Bf[ks].s, acc0, 0, 0, 0);
                acc1 = __builtin_amdgcn_mfma_f32_16x16x32_bf16(a1, Bf[ks].s, acc1, 0, 0, 0);
            }
        }

        // activations: lanes l<32 hold i (acc0) / g (acc1); f/o at lane+32
        float hreg[4];
#pragma unroll
        for (int r = 0; r < 4; ++r) {
            float gf = __shfl_down(acc0[r], 32, 64);
            float go = __shfl_down(acc1[r], 32, 64);
            float is = sigf(acc0[r]);
            float fs = sigf(gf);
            float gv = tanhf(acc1[r]);
            float os = sigf(go);
            c0[r] = fs * c0[r] + is * gv;
            hreg[r] = os * tanhf(c0[r]);
        }

        if (l < 32 && b16 < BB) {
            const int ib = I0 + kg * 4;   // kg in {0,1}
            *(float4*)(hall + ((size_t)t * BB + b16) * HH + ib) =
                make_float4(hreg[0], hreg[1], hreg[2], hreg[3]);
            u64 pk = (u64)f2bf(hreg[0]) | ((u64)f2bf(hreg[1]) << 16) |
                     ((u64)f2bf(hreg[2]) << 32) | ((u64)f2bf(hreg[3]) << 48);
            if (t >= SS)   // decoder h in bf16 for k_vocab (plain; flushed at end)
                *(u64*)(abf + ((size_t)(t - SS) * BB + b16) * HH + ib) = pk;
            if (t < NTOK - 1) {
                unsigned short* hdst = hbf + (t & 1) * (BB * HH) + (size_t)b16 * HH + ib;
                asm volatile("global_store_dwordx2 %0, %1, off sc0 sc1"
                             :: "v"(hdst), "v"(pk) : "memory");
            }
        }

        if (t < NTOK - 1) {
            // wave-level drain of this wave's publishes, then raise OWN flag dword
            asm volatile("s_waitcnt vmcnt(0)" ::: "memory");
            if (l == 0) {
                unsigned fv = (unsigned)(t + 1);
                asm volatile("global_store_dword %0, %1, off sc0 sc1"
                             :: "v"(myflag), "v"(fv) : "memory");
            }
        }
    }
}

// ============ Kernel 3: Q = tanh(Hdec @ W_att^T). grid TM, block 256 ============
__global__ void __launch_bounds__(256) k_q(const float* __restrict__ hall,
                                           const float* __restrict__ Watt,
                                           float* __restrict__ q) {
    __shared__ float hb[8 * 516];
    const int t = blockIdx.x, tid = threadIdx.x;
    const float* hdec = hall + (size_t)(SS + t) * (BB * HH);
    for (int e = tid; e < BB * HH; e += 256)
        hb[(e >> 9) * 516 + (e & 511)] = hdec[e];
    __syncthreads();

    for (int oi = tid; oi < BB * HH; oi += 256) {
        int b = oi & 7, ii = oi >> 3;
        const float4* w4 = (const float4*)(Watt + (size_t)ii * HH);
        const float4* h4 = (const float4*)(hb + b * 516);
        float acc = 0.f;
        for (int k4 = 0; k4 < HH / 4; ++k4) {
            float4 w = w4[k4], h = h4[k4];
            acc += w.x * h.x + w.y * h.y + w.z * h.z + w.w * h.w;
        }
        q[(size_t)(t * BB + b) * HH + ii] = tanhf(acc);
    }
}

// ============ Kernel 4: attention scores + softmax + pointer gather ============
__global__ void __launch_bounds__(256) k_att(const float* __restrict__ hall,
                                             const float* __restrict__ q,
                                             const float* __restrict__ sent,
                                             const int* __restrict__ src,
                                             const int* __restrict__ tgt,
                                             float* __restrict__ pptr,
                                             float* __restrict__ asent) {
    __shared__ float qs[HH];
    __shared__ float av[256];
    __shared__ float red[256];
    const int t = blockIdx.x, b = blockIdx.y, tid = threadIdx.x;

    for (int e = tid; e < HH; e += 256) qs[e] = q[(size_t)(t * BB + b) * HH + e];
    __syncthreads();

    const int j = tid;
    float acc = NEGF;
    if (j < SS + TM + 1) {
        bool valid = (j < SS + t + 1) || (j == SS + TM);
        if (valid) {
            const float* vptr = (j < SS + TM) ? (hall + (size_t)(j * BB + b) * HH) : sent;
            const float4* v4 = (const float4*)vptr;
            const float4* q4 = (const float4*)qs;
            float a = 0.f;
            for (int k4 = 0; k4 < HH / 4; ++k4) {
                float4 v = v4[k4], qq = q4[k4];
                a += v.x * qq.x + v.y * qq.y + v.z * qq.z + v.w * qq.w;
            }
            acc = a;
        }
    }
    red[tid] = acc;
    __syncthreads();
    for (int s2 = 128; s2 > 0; s2 >>= 1) {
        if (tid < s2) red[tid] = fmaxf(red[tid], red[tid + s2]);
        __syncthreads();
    }
    float m = red[0];
    __syncthreads();
    float e = __expf(acc - m);
    red[tid] = e;
    __syncthreads();
    for (int s2 = 128; s2 > 0; s2 >>= 1) {
        if (tid < s2) red[tid] += red[tid + s2];
        __syncthreads();
    }
    float denom = red[0];
    __syncthreads();
    float a = e / denom;
    av[tid] = a;
    __syncthreads();

    const int vs = tgt[(t + 1) * BB + b];
    float contrib = 0.f;
    if (j < SS) {
        if (src[j * BB + b] == vs) contrib += av[j];        // a_src
        if (tgt[j * BB + b] == vs) contrib += av[SS + j];   // a_tgt
    }
    red[tid] = contrib;
    __syncthreads();
    for (int s2 = 128; s2 > 0; s2 >>= 1) {
        if (tid < s2) red[tid] += red[tid + s2];
        __syncthreads();
    }
    if (tid == 0) {
        pptr[t * BB + b]  = red[0];
        asent[t * BB + b] = av[SS + TM];
    }
}

// ============ Kernel 5: vocab softmax stats via bf16 MFMA ============
__global__ void __launch_bounds__(256) k_vocab_mfma(const unsigned short* __restrict__ Abf,
                                                    const unsigned short* __restrict__ Wbf,
                                                    const int* __restrict__ tgt,
                                                    float* __restrict__ ssum,
                                                    float* __restrict__ lstar) {
    const int tid  = threadIdx.x;
    const int wave = tid >> 6;
    const int lane = tid & 63;
    const int r16  = lane & 15;
    const int kg   = lane >> 4;          // 0..3
    const int n0   = blockIdx.x * 64;

    const unsigned short* b0 = Wbf + (size_t)(n0 +  0 + r16) * HH + kg * 8;
    const unsigned short* b1 = Wbf + (size_t)(n0 + 16 + r16) * HH + kg * 8;
    const unsigned short* b2 = Wbf + (size_t)(n0 + 32 + r16) * HH + kg * 8;
    const unsigned short* b3 = Wbf + (size_t)(n0 + 48 + r16) * HH + kg * 8;

    for (int pass = 0; pass < 12; ++pass) {
        const int row0 = pass * 64 + wave * 16;
        const unsigned short* arow = Abf + (size_t)(row0 + r16) * HH + kg * 8;

        f32x4 acc0 = {0.f,0.f,0.f,0.f}, acc1 = acc0, acc2 = acc0, acc3 = acc0;
#pragma unroll
        for (int ks = 0; ks < 16; ++ks) {
            short8 a = *(const short8*)(arow + ks * 32);
            acc0 = __builtin_amdgcn_mfma_f32_16x16x32_bf16(a, *(const short8*)(b0 + ks * 32), acc0, 0, 0, 0);
            acc1 = __builtin_amdgcn_mfma_f32_16x16x32_bf16(a, *(const short8*)(b1 + ks * 32), acc1, 0, 0, 0);
            acc2 = __builtin_amdgcn_mfma_f32_16x16x32_bf16(a, *(const short8*)(b2 + ks * 32), acc2, 0, 0, 0);
            acc3 = __builtin_amdgcn_mfma_f32_16x16x32_bf16(a, *(const short8*)(b3 + ks * 32), acc3, 0, 0, 0);
        }

#pragma unroll
        for (int reg = 0; reg < 4; ++reg) {
            const int rowg = row0 + 4 * kg + reg;
            const int vs = tgt[BB + rowg];
            int cg;
            cg = n0 +  0 + r16; if (cg == vs) lstar[rowg] = acc0[reg];
            cg = n0 + 16 + r16; if (cg == vs) lstar[rowg] = acc1[reg];
            cg = n0 + 32 + r16; if (cg == vs) lstar[rowg] = acc2[reg];
            cg = n0 + 48 + r16; if (cg == vs) lstar[rowg] = acc3[reg];

            float v = __expf(acc0[reg]) + __expf(acc1[reg]) +
                      __expf(acc2[reg]) + __expf(acc3[reg]);
            v += __shfl_xor(v, 1, 64);
            v += __shfl_xor(v, 2, 64);
            v += __shfl_xor(v, 4, 64);
            v += __shfl_xor(v, 8, 64);
            if (r16 == 0) atomicAdd(&ssum[rowg], v);
        }
    }
}

// ============ Kernel 5-fallback: f32 vocab stats (used if ws too small) ============
__global__ void __launch_bounds__(256) k_vocab_f32(const float* __restrict__ hall,
                                                   const float* __restrict__ Wread,
                                                   const int* __restrict__ tgt,
                                                   float* __restrict__ ssum,
                                                   float* __restrict__ lstar) {
    __shared__ float hs[32 * HH];   // 64 KB
    const int tid = threadIdx.x;
    const int v0 = blockIdx.x * 512 + tid * 2;
    const int v1 = v0 + 1;
    const bool g0 = v0 < VV, g1 = v1 < VV;
    const float4* w40 = (const float4*)(Wread + (size_t)(g0 ? v0 : 0) * HH);
    const float4* w41 = (const float4*)(Wread + (size_t)(g1 ? v1 : 0) * HH);
    const int rbase0 = blockIdx.y * 128;

    for (int ch = 0; ch < 4; ++ch) {
        const int rbase = rbase0 + ch * 32;
        const float4* sp4 = (const float4*)(hall + ((size_t)SS * BB + rbase) * HH);
        float4* hs4 = (float4*)hs;
        for (int e = tid; e < 32 * HH / 4; e += 256) hs4[e] = sp4[e];
        __syncthreads();

        float acc0[32], acc1[32];
#pragma unroll
        for (int r = 0; r < 32; ++r) { acc0[r] = 0.f; acc1[r] = 0.f; }

        for (int k4 = 0; k4 < HH / 4; ++k4) {
            float4 w0 = w40[k4];
            float4 w1 = w41[k4];
#pragma unroll
            for (int r = 0; r < 32; ++r) {
                float4 h = *((const float4*)(hs + r * HH + k4 * 4));
                acc0[r] += w0.x * h.x + w0.y * h.y + w0.z * h.z + w0.w * h.w;
                acc1[r] += w1.x * h.x + w1.y * h.y + w1.z * h.z + w1.w * h.w;
            }
        }

#pragma unroll
        for (int r = 0; r < 32; ++r) {
            const int row = rbase + r;
            float val = 0.f;
            if (g0) val += __expf(acc0[r]);
            if (g1) val += __expf(acc1[r]);
#pragma unroll
            for (int d = 32; d > 0; d >>= 1) val += __shfl_xor(val, d, 64);
            if ((tid & 63) == 0) atomicAdd(&ssum[row], val);
            const int vs = tgt[row + BB];
            if (g0 && v0 == vs) lstar[row] = acc0[r];
            else if (g1 && v1 == vs) lstar[row] = acc1[r];
        }
        __syncthreads();
    }
}

// ============ Kernel 6: gold log-likelihoods + per-batch sums ============
__global__ void __launch_bounds__(768) k_final(const float* __restrict__ pptr,
                                               const float* __restrict__ asent,
                                               const float* __restrict__ ssum,
                                               const float* __restrict__ lstar,
                                               const int* __restrict__ tgt,
                                               float* __restrict__ out) {
    __shared__ float g[TM * BB], gp[TM * BB];
    const int tid = threadIdx.x;          // = t*8+b
    const int vs = tgt[tid + BB];
    const float pv = __expf(lstar[tid]) / ssum[tid];
    const float ps = pptr[tid];
    const float as = asent[tid];
    if (vs != 0) {
        g[tid]  = logf(ps + pv * as);
        gp[tid] = logf(ps + as);
    } else {
        g[tid] = 0.f; gp[tid] = 0.f;
    }
    __syncthreads();
    if (tid < BB) {
        float s1 = 0.f, s2 = 0.f;
        for (int t = 0; t < TM; ++t) { s1 += g[t * BB + tid]; s2 += gp[t * BB + tid]; }
        out[tid] = s1;
        out[BB + tid] = s2;
    }
}

extern "C" void kernel_launch(void* const* d_in, const int* in_sizes, int n_in,
                              void* d_out, int out_size, void* d_ws, size_t ws_size,
                              hipStream_t stream) {
    (void)in_sizes; (void)n_in; (void)out_size;
    const int*   src   = (const int*)d_in[0];
    const int*   tgt   = (const int*)d_in[1];
    const float* emb   = (const float*)d_in[2];
    const float* Wih   = (const float*)d_in[3];
    const float* Whh   = (const float*)d_in[4];
    const float* bih   = (const float*)d_in[5];
    const float* bhh   = (const float*)d_in[6];
    const float* Watt  = (const float*)d_in[7];
    const float* sent  = (const float*)d_in[8];
    const float* Wread = (const float*)d_in[9];
    float* ws  = (float*)d_ws;
    float* out = (float*)d_out;

    const bool use_mfma_vocab = ws_size >= NEED_F * sizeof(float);

    // zero SSUM + LSTAR + FLAGS (contiguous: 768+768+1024)
    (void)hipMemsetAsync((void*)(ws + SSUM_OFF), 0, (size_t)2560 * sizeof(float), stream);

    k_prep<<<dim3(NPREP), 256, 0, stream>>>(
        src, tgt, emb, Wih, bih, bhh, Whh, Wread,
        ws + XIH_OFF, (unsigned short*)(ws + WHHBF_OFF), (unsigned short*)(ws + WBF_OFF));

    {
        const float* xih = ws + XIH_OFF;
        const unsigned short* whhbf = (const unsigned short*)(ws + WHHBF_OFF);
        float* hall = ws + HALL_OFF;
        unsigned short* hbf = (unsigned short*)(ws + HBF_OFF);
        unsigned short* abf = (unsigned short*)(ws + ABF_OFF);
        unsigned* flags = (unsigned*)(ws + FLAG_OFF);
        void* args[] = { (void*)&xih, (void*)&whhbf, (void*)&hall,
                         (void*)&hbf, (void*)&abf, (void*)&flags };
        (void)hipLaunchCooperativeKernel((void*)k_lstm, dim3(LBLK), dim3(256), args,
                                         131072, stream);
    }

    k_q<<<dim3(TM), 256, 0, stream>>>(ws + HALL_OFF, Watt, ws + Q_OFF);

    k_att<<<dim3(TM, BB), 256, 0, stream>>>(ws + HALL_OFF, ws + Q_OFF, sent,
                                            src, tgt, ws + PPTR_OFF, ws + ASENT_OFF);

    if (use_mfma_vocab) {
        k_vocab_mfma<<<dim3(VV / 64), 256, 0, stream>>>(
            (const unsigned short*)(ws + ABF_OFF),
            (const unsigned short*)(ws + WBF_OFF),
            tgt, ws + SSUM_OFF, ws + LSTAR_OFF);
    } else {
        k_vocab_f32<<<dim3(63, 6), 256, 0, stream>>>(ws + HALL_OFF, Wread, tgt,
                                                     ws + SSUM_OFF, ws + LSTAR_OFF);
    }

    k_final<<<dim3(1), dim3(TM * BB), 0, stream>>>(ws + PPTR_OFF, ws + ASENT_OFF,
                                                   ws + SSUM_OFF, ws + LSTAR_OFF,
                                                   tgt, out);
}

// Round 14
// 1292.655 us; speedup vs baseline: 1.1536x; 1.1536x over previous
//
#include <hip/hip_runtime.h>
#include <math.h>

#define SS   96
#define TM   96
#define BB   8
#define VV   32000
#define EE   256
#define HH   512
#define NTOK (SS + TM)     // 192
#define G4   (4 * HH)      // 2048
#define NEGF (-1e30f)
#define LBLK 16            // k_lstm blocks (64 waves)

// k_prep unit counts
#define NXIH  768                      // 96 token-tiles x 8 row-blocks
#define NCVTW 512                      // Whh: 1,048,576 f / 2048
#define NCVTR 8000                     // Wread: 16,384,000 f / 2048
#define NPREP (NXIH + NCVTW + NCVTR)   // 9280

typedef __attribute__((ext_vector_type(8))) short short8;
typedef __attribute__((ext_vector_type(4))) float f32x4;
typedef __attribute__((ext_vector_type(4))) unsigned uint32x4;
typedef unsigned long long u64;

// ---- workspace layout (float offsets) ----
#define XIH_OFF   ((size_t)0)
#define XIH_SZ    ((size_t)NTOK * BB * G4)       // 3,145,728 f
#define HALL_OFF  (XIH_OFF + XIH_SZ)
#define HALL_SZ   ((size_t)NTOK * BB * HH)       // 786,432 f
#define Q_OFF     (HALL_OFF + HALL_SZ)
#define Q_SZ      ((size_t)TM * BB * HH)         // 393,216 f
#define PPTR_OFF  (Q_OFF + Q_SZ)
#define ASENT_OFF (PPTR_OFF + (size_t)(TM * BB))
#define SSUM_OFF  (ASENT_OFF + (size_t)(TM * BB))
#define LSTAR_OFF (SSUM_OFF + (size_t)(TM * BB))
#define FLAG_OFF  (LSTAR_OFF + (size_t)(TM * BB))   // 16 block flags x 16 u32
#define HBF_OFF   (FLAG_OFF + (size_t)1024)
#define HBF_SZF   ((size_t)2 * BB * HH / 2)         // 4,096 f (2 x 8 x 512 bf16)
#define WHHBF_OFF (HBF_OFF + HBF_SZF)
#define WHHBF_SZF ((size_t)G4 * HH / 2)             // 524,288 f
#define ABF_OFF   (WHHBF_OFF + WHHBF_SZF)
#define ABF_SZF   ((size_t)(TM * BB) * HH / 2)      // 196,608 f
#define WBF_OFF   (ABF_OFF + ABF_SZF)
#define WBF_SZF   ((size_t)VV * HH / 2)             // 8,192,000 f
#define NEED_F    (WBF_OFF + WBF_SZF)

__device__ __forceinline__ float sigf(float x) { return 1.f / (1.f + __expf(-x)); }

__device__ __forceinline__ unsigned short f2bf(float x) {
    unsigned bits = __float_as_uint(x);
    bits += 0x7FFFu + ((bits >> 16) & 1u);   // RNE
    return (unsigned short)(bits >> 16);
}

// ============ Kernel 1: prep = xih tiles + Whh cvt + Wread cvt (one launch) ============
__global__ void __launch_bounds__(256) k_prep(const int* __restrict__ src,
                                              const int* __restrict__ tgt,
                                              const float* __restrict__ emb,
                                              const float* __restrict__ Wih,
                                              const float* __restrict__ bih,
                                              const float* __restrict__ bhh,
                                              const float* __restrict__ Whh,
                                              const float* __restrict__ Wread,
                                              float* __restrict__ xih,
                                              unsigned short* __restrict__ whhbf,
                                              unsigned short* __restrict__ wbf) {
    __shared__ float xs[16 * EE];   // 16 KB
    const int bid = blockIdx.x;
    const int tid = threadIdx.x;

    if (bid < NXIH) {
        const int tok0 = (bid >> 3) * 16;
        const int row0 = (bid & 7) * 256;
        for (int e = tid; e < 16 * EE; e += 256) {
            int tk = e >> 8, k = e & 255;
            int tau = tok0 + tk;
            int idx = (tau < SS * BB) ? src[tau] : tgt[tau - SS * BB];
            xs[tk * EE + k] = (idx == 0) ? 0.f : emb[(size_t)idx * EE + k];
        }
        __syncthreads();

        const int row = row0 + tid;
        const float bias = bih[row] + bhh[row];
        float acc[16];
#pragma unroll
        for (int r = 0; r < 16; ++r) acc[r] = bias;
        const float4* w4 = (const float4*)(Wih + (size_t)row * EE);
        for (int k4 = 0; k4 < EE / 4; ++k4) {
            float4 w = w4[k4];
#pragma unroll
            for (int r = 0; r < 16; ++r) {
                float4 x = *((const float4*)&xs[r * EE + k4 * 4]);
                acc[r] += w.x * x.x + w.y * x.y + w.z * x.z + w.w * x.w;
            }
        }
#pragma unroll
        for (int r = 0; r < 16; ++r)
            xih[(size_t)(tok0 + r) * G4 + row] = acc[r];
        return;
    }

    const float* srcp;
    unsigned short* dstp;
    size_t base;
    if (bid < NXIH + NCVTW) { srcp = Whh;   dstp = whhbf; base = (size_t)(bid - NXIH) * 2048; }
    else                    { srcp = Wread; dstp = wbf;   base = (size_t)(bid - NXIH - NCVTW) * 2048; }
    base += (size_t)tid * 8;
    float4 f0 = *(const float4*)(srcp + base);
    float4 f1 = *(const float4*)(srcp + base + 4);
    uint4 o;
    o.x = (unsigned)f2bf(f0.x) | ((unsigned)f2bf(f0.y) << 16);
    o.y = (unsigned)f2bf(f0.z) | ((unsigned)f2bf(f0.w) << 16);
    o.z = (unsigned)f2bf(f1.x) | ((unsigned)f2bf(f1.y) << 16);
    o.w = (unsigned)f2bf(f1.z) | ((unsigned)f2bf(f1.w) << 16);
    *(uint4*)(dstp + base) = o;
}

// ============ Kernel 2: LSTM scan — r11 VERBATIM structure, REGULAR launch ============
// 16 blocks x 256 thr. LDS-resident Whh (static 128 KB), 16 block-flags, 2 in-loop
// barriers. Best measured: 840 µs (r11). Regular launch (no cooperative): 16 blocks
// << 256 CUs are trivially co-resident; no grid.sync used, only flag spins.
__global__ void __launch_bounds__(256, 1) k_lstm(const float* __restrict__ xih,
                                                 const unsigned short* __restrict__ whhbf,
                                                 float* __restrict__ hall,
                                                 unsigned short* __restrict__ hbf,
                                                 unsigned short* __restrict__ abf,
                                                 unsigned* __restrict__ flags) {
    __shared__ short lA[65536];   // 131072 B static
    const int tid = threadIdx.x;
    const int wv  = tid >> 6;
    const int l   = tid & 63;
    const int b16 = l & 15;          // MFMA col = batch (cols 8..15 don't-care)
    const int kg  = l >> 4;          // 0..3
    const int bb  = b16 & 7;
    const int bx  = blockIdx.x;
    const int I0  = bx * 32 + wv * 8;

    // ---- stage A fragments into LDS (once; r9-verified layout) ----
    const int j = b16;
    const unsigned short* a0p = whhbf + ((size_t)((j >> 3) * HH + I0 + (j & 7))) * HH + kg * 8;
    const unsigned short* a1p = whhbf + ((size_t)((2 + (j >> 3)) * HH + I0 + (j & 7))) * HH + kg * 8;
    short* lA0 = lA + (((size_t)wv * 2 + 0) * 16 * 64 + l) * 8;
    short* lA1 = lA + (((size_t)wv * 2 + 1) * 16 * 64 + l) * 8;
#pragma unroll
    for (int ks = 0; ks < 16; ++ks) {
        *(short8*)(lA0 + ks * 512) = *(const short8*)(a0p + ks * 32);
        *(short8*)(lA1 + ks * 512) = *(const short8*)(a1p + ks * 32);
    }
    __syncthreads();

    const int xgate0 = (kg >> 1);        // 0:i 1:f
    const int xgate1 = 2 + (kg >> 1);    // 2:g 3:o
    const int xi     = I0 + (kg & 1) * 4;

    float c0[4] = {0.f, 0.f, 0.f, 0.f};
    union fragu { uint32x4 u4; short8 s; };

    for (int t = 0; t < NTOK; ++t) {
        const float* xb = xih + ((size_t)t * BB + bb) * G4;
        float4 x0 = *(const float4*)(xb + xgate0 * HH + xi);
        float4 x1 = *(const float4*)(xb + xgate1 * HH + xi);

        fragu Bf[16];
        if (t > 0) {
            // poll the 16 block flags (lane l < 16 polls flag l)
            if (l < 16) {
                while (__hip_atomic_load(&flags[(size_t)l * 16], __ATOMIC_RELAXED,
                                         __HIP_MEMORY_SCOPE_AGENT) < (unsigned)t) {}
            }
            // batched B loads (h_{t-1}, parity (t-1)&1), one wait for all 16
            const unsigned short* hsrc =
                hbf + ((t - 1) & 1) * (BB * HH) + (size_t)bb * HH + kg * 8;
#pragma unroll
            for (int ks = 0; ks < 16; ++ks)
                asm volatile("global_load_dwordx4 %0, %1, off sc0 sc1"
                             : "=v"(Bf[ks].u4) : "v"(hsrc + ks * 32) : "memory");
            asm volatile("s_waitcnt vmcnt(0)" ::: "memory");
            __builtin_amdgcn_sched_barrier(0);
        }

        f32x4 acc0 = {x0.x, x0.y, x0.z, x0.w};
        f32x4 acc1 = {x1.x, x1.y, x1.z, x1.w};
        if (t > 0) {
#pragma unroll
            for (int ks = 0; ks < 16; ++ks) {
                short8 a0 = *(const short8*)(lA0 + ks * 512);
                short8 a1 = *(const short8*)(lA1 + ks * 512);
                acc0 = __builtin_amdgcn_mfma_f32_16x16x32_bf16(a0, Bf[ks].s, acc0, 0, 0, 0);
                acc1 = __builtin_amdgcn_mfma_f32_16x16x32_bf16(a1, Bf[ks].s, acc1, 0, 0, 0);
            }
        }

        float hreg[4];
#pragma unroll
        for (int r = 0; r < 4; ++r) {
            float gf = __shfl_down(acc0[r], 32, 64);
            float go = __shfl_down(acc1[r], 32, 64);
            float is = sigf(acc0[r]);
            float fs = sigf(gf);
            float gv = tanhf(acc1[r]);
            float os = sigf(go);
            c0[r] = fs * c0[r] + is * gv;
            hreg[r] = os * tanhf(c0[r]);
        }

        if (l < 32 && b16 < BB) {
            const int ib = I0 + kg * 4;   // kg in {0,1}
            *(float4*)(hall + ((size_t)t * BB + b16) * HH + ib) =
                make_float4(hreg[0], hreg[1], hreg[2], hreg[3]);
            u64 pk = (u64)f2bf(hreg[0]) | ((u64)f2bf(hreg[1]) << 16) |
                     ((u64)f2bf(hreg[2]) << 32) | ((u64)f2bf(hreg[3]) << 48);
            if (t >= SS)   // decoder h in bf16 for k_vocab
                *(u64*)(abf + ((size_t)(t - SS) * BB + b16) * HH + ib) = pk;
            if (t < NTOK - 1) {
                unsigned short* hdst = hbf + (t & 1) * (BB * HH) + (size_t)b16 * HH + ib;
                asm volatile("global_store_dwordx2 %0, %1, off sc0 sc1"
                             :: "v"(hdst), "v"(pk) : "memory");
            }
        }

        if (t < NTOK - 1) {
            asm volatile("s_waitcnt vmcnt(0)" ::: "memory");
            __syncthreads();
            if (tid == 0)
                __hip_atomic_store(&flags[(size_t)bx * 16], (unsigned)(t + 1),
                                   __ATOMIC_RELAXED, __HIP_MEMORY_SCOPE_AGENT);
        }
    }
}

// ============ Kernel 3: Q = tanh(Hdec @ W_att^T). grid TM, block 256 ============
__global__ void __launch_bounds__(256) k_q(const float* __restrict__ hall,
                                           const float* __restrict__ Watt,
                                           float* __restrict__ q) {
    __shared__ float hb[8 * 516];
    const int t = blockIdx.x, tid = threadIdx.x;
    const float* hdec = hall + (size_t)(SS + t) * (BB * HH);
    for (int e = tid; e < BB * HH; e += 256)
        hb[(e >> 9) * 516 + (e & 511)] = hdec[e];
    __syncthreads();

    for (int oi = tid; oi < BB * HH; oi += 256) {
        int b = oi & 7, ii = oi >> 3;
        const float4* w4 = (const float4*)(Watt + (size_t)ii * HH);
        const float4* h4 = (const float4*)(hb + b * 516);
        float acc = 0.f;
        for (int k4 = 0; k4 < HH / 4; ++k4) {
            float4 w = w4[k4], h = h4[k4];
            acc += w.x * h.x + w.y * h.y + w.z * h.z + w.w * h.w;
        }
        q[(size_t)(t * BB + b) * HH + ii] = tanhf(acc);
    }
}

// ============ Kernel 4: attention scores + softmax + pointer gather ============
__global__ void __launch_bounds__(256) k_att(const float* __restrict__ hall,
                                             const float* __restrict__ q,
                                             const float* __restrict__ sent,
                                             const int* __restrict__ src,
                                             const int* __restrict__ tgt,
                                             float* __restrict__ pptr,
                                             float* __restrict__ asent) {
    __shared__ float qs[HH];
    __shared__ float av[256];
    __shared__ float red[256];
    const int t = blockIdx.x, b = blockIdx.y, tid = threadIdx.x;

    for (int e = tid; e < HH; e += 256) qs[e] = q[(size_t)(t * BB + b) * HH + e];
    __syncthreads();

    const int j = tid;
    float acc = NEGF;
    if (j < SS + TM + 1) {
        bool valid = (j < SS + t + 1) || (j == SS + TM);
        if (valid) {
            const float* vptr = (j < SS + TM) ? (hall + (size_t)(j * BB + b) * HH) : sent;
            const float4* v4 = (const float4*)vptr;
            const float4* q4 = (const float4*)qs;
            float a = 0.f;
            for (int k4 = 0; k4 < HH / 4; ++k4) {
                float4 v = v4[k4], qq = q4[k4];
                a += v.x * qq.x + v.y * qq.y + v.z * qq.z + v.w * qq.w;
            }
            acc = a;
        }
    }
    red[tid] = acc;
    __syncthreads();
    for (int s2 = 128; s2 > 0; s2 >>= 1) {
        if (tid < s2) red[tid] = fmaxf(red[tid], red[tid + s2]);
        __syncthreads();
    }
    float m = red[0];
    __syncthreads();
    float e = __expf(acc - m);
    red[tid] = e;
    __syncthreads();
    for (int s2 = 128; s2 > 0; s2 >>= 1) {
        if (tid < s2) red[tid] += red[tid + s2];
        __syncthreads();
    }
    float denom = red[0];
    __syncthreads();
    float a = e / denom;
    av[tid] = a;
    __syncthreads();

    const int vs = tgt[(t + 1) * BB + b];
    float contrib = 0.f;
    if (j < SS) {
        if (src[j * BB + b] == vs) contrib += av[j];        // a_src
        if (tgt[j * BB + b] == vs) contrib += av[SS + j];   // a_tgt
    }
    red[tid] = contrib;
    __syncthreads();
    for (int s2 = 128; s2 > 0; s2 >>= 1) {
        if (tid < s2) red[tid] += red[tid + s2];
        __syncthreads();
    }
    if (tid == 0) {
        pptr[t * BB + b]  = red[0];
        asent[t * BB + b] = av[SS + TM];
    }
}

// ============ Kernel 5: vocab softmax stats via bf16 MFMA, B staged in LDS ============
// 500 blocks x 64 cols. B-panel (64 cols x 512 k bf16 = 64 KB) staged ONCE into LDS
// in fragment layout; 12 row-passes read B via conflict-free ds_read_b128 instead of
// re-streaming 64 KB x 12 from global with per-MFMA waits.
__global__ void __launch_bounds__(256) k_vocab_mfma(const unsigned short* __restrict__ Abf,
                                                    const unsigned short* __restrict__ Wbf,
                                                    const int* __restrict__ tgt,
                                                    float* __restrict__ ssum,
                                                    float* __restrict__ lstar) {
    __shared__ short lB[32768];   // 64 KB: slot (cb*16+ks) x 64 lanes x 8 shorts
    const int tid  = threadIdx.x;
    const int lane = tid & 63;
    const int r16  = lane & 15;
    const int kg   = lane >> 4;          // 0..3
    const int n0   = blockIdx.x * 64;

    // stage B: entry s = (slot, ll): slot = cb*16+ks; value = Wbf[(n0+cb*16+(ll&15))*HH + ks*32 + (ll>>4)*8]
    for (int s = tid; s < 4096; s += 256) {
        const int slot = s >> 6;
        const int cb = slot >> 4, ks = slot & 15;
        const int ll = s & 63;
        const int rr = ll & 15, kk = ll >> 4;
        *(short8*)(lB + (size_t)s * 8) =
            *(const short8*)(Wbf + (size_t)(n0 + cb * 16 + rr) * HH + ks * 32 + kk * 8);
    }
    __syncthreads();

    const short* lBme = lB + (size_t)lane * 8;   // lane-local base; slot stride 512 shorts

    for (int pass = 0; pass < 12; ++pass) {
        const int row0 = pass * 64 + (tid >> 6) * 16;
        const unsigned short* arow = Abf + (size_t)(row0 + r16) * HH + kg * 8;

        f32x4 acc0 = {0.f,0.f,0.f,0.f}, acc1 = acc0, acc2 = acc0, acc3 = acc0;
#pragma unroll
        for (int ks = 0; ks < 16; ++ks) {
            short8 a = *(const short8*)(arow + ks * 32);
            acc0 = __builtin_amdgcn_mfma_f32_16x16x32_bf16(a, *(const short8*)(lBme + (size_t)(0 * 16 + ks) * 512), acc0, 0, 0, 0);
            acc1 = __builtin_amdgcn_mfma_f32_16x16x32_bf16(a, *(const short8*)(lBme + (size_t)(1 * 16 + ks) * 512), acc1, 0, 0, 0);
            acc2 = __builtin_amdgcn_mfma_f32_16x16x32_bf16(a, *(const short8*)(lBme + (size_t)(2 * 16 + ks) * 512), acc2, 0, 0, 0);
            acc3 = __builtin_amdgcn_mfma_f32_16x16x32_bf16(a, *(const short8*)(lBme + (size_t)(3 * 16 + ks) * 512), acc3, 0, 0, 0);
        }

#pragma unroll
        for (int reg = 0; reg < 4; ++reg) {
            const int rowg = row0 + 4 * kg + reg;
            const int vs = tgt[BB + rowg];
            int cg;
            cg = n0 +  0 + r16; if (cg == vs) lstar[rowg] = acc0[reg];
            cg = n0 + 16 + r16; if (cg == vs) lstar[rowg] = acc1[reg];
            cg = n0 + 32 + r16; if (cg == vs) lstar[rowg] = acc2[reg];
            cg = n0 + 48 + r16; if (cg == vs) lstar[rowg] = acc3[reg];

            float v = __expf(acc0[reg]) + __expf(acc1[reg]) +
                      __expf(acc2[reg]) + __expf(acc3[reg]);
            v += __shfl_xor(v, 1, 64);
            v += __shfl_xor(v, 2, 64);
            v += __shfl_xor(v, 4, 64);
            v += __shfl_xor(v, 8, 64);
            if (r16 == 0) atomicAdd(&ssum[rowg], v);
        }
    }
}

// ============ Kernel 5-fallback: f32 vocab stats (used if ws too small) ============
__global__ void __launch_bounds__(256) k_vocab_f32(const float* __restrict__ hall,
                                                   const float* __restrict__ Wread,
                                                   const int* __restrict__ tgt,
                                                   float* __restrict__ ssum,
                                                   float* __restrict__ lstar) {
    __shared__ float hs[32 * HH];   // 64 KB
    const int tid = threadIdx.x;
    const int v0 = blockIdx.x * 512 + tid * 2;
    const int v1 = v0 + 1;
    const bool g0 = v0 < VV, g1 = v1 < VV;
    const float4* w40 = (const float4*)(Wread + (size_t)(g0 ? v0 : 0) * HH);
    const float4* w41 = (const float4*)(Wread + (size_t)(g1 ? v1 : 0) * HH);
    const int rbase0 = blockIdx.y * 128;

    for (int ch = 0; ch < 4; ++ch) {
        const int rbase = rbase0 + ch * 32;
        const float4* sp4 = (const float4*)(hall + ((size_t)SS * BB + rbase) * HH);
        float4* hs4 = (float4*)hs;
        for (int e = tid; e < 32 * HH / 4; e += 256) hs4[e] = sp4[e];
        __syncthreads();

        float acc0[32], acc1[32];
#pragma unroll
        for (int r = 0; r < 32; ++r) { acc0[r] = 0.f; acc1[r] = 0.f; }

        for (int k4 = 0; k4 < HH / 4; ++k4) {
            float4 w0 = w40[k4];
            float4 w1 = w41[k4];
#pragma unroll
            for (int r = 0; r < 32; ++r) {
                float4 h = *((const float4*)(hs + r * HH + k4 * 4));
                acc0[r] += w0.x * h.x + w0.y * h.y + w0.z * h.z + w0.w * h.w;
                acc1[r] += w1.x * h.x + w1.y * h.y + w1.z * h.z + w1.w * h.w;
            }
        }

#pragma unroll
        for (int r = 0; r < 32; ++r) {
            const int row = rbase + r;
            float val = 0.f;
            if (g0) val += __expf(acc0[r]);
            if (g1) val += __expf(acc1[r]);
#pragma unroll
            for (int d = 32; d > 0; d >>= 1) val += __shfl_xor(val, d, 64);
            if ((tid & 63) == 0) atomicAdd(&ssum[row], val);
            const int vs = tgt[row + BB];
            if (g0 && v0 == vs) lstar[row] = acc0[r];
            else if (g1 && v1 == vs) lstar[row] = acc1[r];
        }
        __syncthreads();
    }
}

// ============ Kernel 6: gold log-likelihoods + per-batch sums ============
__global__ void __launch_bounds__(768) k_final(const float* __restrict__ pptr,
                                               const float* __restrict__ asent,
                                               const float* __restrict__ ssum,
                                               const float* __restrict__ lstar,
                                               const int* __restrict__ tgt,
                                               float* __restrict__ out) {
    __shared__ float g[TM * BB], gp[TM * BB];
    const int tid = threadIdx.x;          // = t*8+b
    const int vs = tgt[tid + BB];
    const float pv = __expf(lstar[tid]) / ssum[tid];
    const float ps = pptr[tid];
    const float as = asent[tid];
    if (vs != 0) {
        g[tid]  = logf(ps + pv * as);
        gp[tid] = logf(ps + as);
    } else {
        g[tid] = 0.f; gp[tid] = 0.f;
    }
    __syncthreads();
    if (tid < BB) {
        float s1 = 0.f, s2 = 0.f;
        for (int t = 0; t < TM; ++t) { s1 += g[t * BB + tid]; s2 += gp[t * BB + tid]; }
        out[tid] = s1;
        out[BB + tid] = s2;
    }
}

extern "C" void kernel_launch(void* const* d_in, const int* in_sizes, int n_in,
                              void* d_out, int out_size, void* d_ws, size_t ws_size,
                              hipStream_t stream) {
    (void)in_sizes; (void)n_in; (void)out_size;
    const int*   src   = (const int*)d_in[0];
    const int*   tgt   = (const int*)d_in[1];
    const float* emb   = (const float*)d_in[2];
    const float* Wih   = (const float*)d_in[3];
    const float* Whh   = (const float*)d_in[4];
    const float* bih   = (const float*)d_in[5];
    const float* bhh   = (const float*)d_in[6];
    const float* Watt  = (const float*)d_in[7];
    const float* sent  = (const float*)d_in[8];
    const float* Wread = (const float*)d_in[9];
    float* ws  = (float*)d_ws;
    float* out = (float*)d_out;

    const bool use_mfma_vocab = ws_size >= NEED_F * sizeof(float);

    // zero SSUM + LSTAR + FLAGS (contiguous: 768+768+1024)
    (void)hipMemsetAsync((void*)(ws + SSUM_OFF), 0, (size_t)2560 * sizeof(float), stream);

    k_prep<<<dim3(NPREP), 256, 0, stream>>>(
        src, tgt, emb, Wih, bih, bhh, Whh, Wread,
        ws + XIH_OFF, (unsigned short*)(ws + WHHBF_OFF), (unsigned short*)(ws + WBF_OFF));

    // REGULAR launch (16 blocks trivially co-resident; no grid.sync inside)
    k_lstm<<<dim3(LBLK), 256, 0, stream>>>(
        ws + XIH_OFF, (const unsigned short*)(ws + WHHBF_OFF), ws + HALL_OFF,
        (unsigned short*)(ws + HBF_OFF), (unsigned short*)(ws + ABF_OFF),
        (unsigned*)(ws + FLAG_OFF));

    k_q<<<dim3(TM), 256, 0, stream>>>(ws + HALL_OFF, Watt, ws + Q_OFF);

    k_att<<<dim3(TM, BB), 256, 0, stream>>>(ws + HALL_OFF, ws + Q_OFF, sent,
                                            src, tgt, ws + PPTR_OFF, ws + ASENT_OFF);

    if (use_mfma_vocab) {
        k_vocab_mfma<<<dim3(VV / 64), 256, 0, stream>>>(
            (const unsigned short*)(ws + ABF_OFF),
            (const unsigned short*)(ws + WBF_OFF),
            tgt, ws + SSUM_OFF, ws + LSTAR_OFF);
    } else {
        k_vocab_f32<<<dim3(63, 6), 256, 0, stream>>>(ws + HALL_OFF, Wread, tgt,
                                                     ws + SSUM_OFF, ws + LSTAR_OFF);
    }

    k_final<<<dim3(1), dim3(TM * BB), 0, stream>>>(ws + PPTR_OFF, ws + ASENT_OFF,
                                                   ws + SSUM_OFF, ws + LSTAR_OFF,
                                                   tgt, out);
}

// Round 15
// 1236.673 us; speedup vs baseline: 1.2058x; 1.0453x over previous
//
#include <hip/hip_runtime.h>
#include <math.h>

#define SS   96
#define TM   96
#define BB   8
#define VV   32000
#define EE   256
#define HH   512
#define NTOK (SS + TM)     // 192
#define G4   (4 * HH)      // 2048
#define NEGF (-1e30f)
#define LBLK 16            // k_lstm blocks (64 waves)
#define NVT  (VV / 64)     // 500 vocab column tiles

// k_prep unit counts
#define NXIH  768                      // 96 token-tiles x 8 row-blocks
#define NCVTW 512                      // Whh: 1,048,576 f / 2048
#define NCVTR 8000                     // Wread: 16,384,000 f / 2048
#define NPREP (NXIH + NCVTW + NCVTR)   // 9280

typedef __attribute__((ext_vector_type(8))) short short8;
typedef __attribute__((ext_vector_type(4))) float f32x4;
typedef __attribute__((ext_vector_type(4))) unsigned uint32x4;
typedef unsigned long long u64;

// ---- workspace layout (float offsets) ----
#define XIH_OFF   ((size_t)0)
#define XIH_SZ    ((size_t)NTOK * BB * G4)       // 3,145,728 f
#define HALL_OFF  (XIH_OFF + XIH_SZ)
#define HALL_SZ   ((size_t)NTOK * BB * HH)       // 786,432 f
#define Q_OFF     (HALL_OFF + HALL_SZ)
#define Q_SZ      ((size_t)TM * BB * HH)         // 393,216 f
#define PPTR_OFF  (Q_OFF + Q_SZ)
#define ASENT_OFF (PPTR_OFF + (size_t)(TM * BB))
#define SSUM_OFF  (ASENT_OFF + (size_t)(TM * BB))
#define LSTAR_OFF (SSUM_OFF + (size_t)(TM * BB))
#define FLAG_OFF  (LSTAR_OFF + (size_t)(TM * BB))   // 16 block flags x 16 u32
#define HBF_OFF   (FLAG_OFF + (size_t)1024)
#define HBF_SZF   ((size_t)2 * BB * HH / 2)         // 4,096 f
#define WHHBF_OFF (HBF_OFF + HBF_SZF)
#define WHHBF_SZF ((size_t)G4 * HH / 2)             // 524,288 f
#define ABF_OFF   (WHHBF_OFF + WHHBF_SZF)
#define ABF_SZF   ((size_t)(TM * BB) * HH / 2)      // 196,608 f
#define WBF_OFF   (ABF_OFF + ABF_SZF)
#define WBF_SZF   ((size_t)VV * HH / 2)             // 8,192,000 f
#define PSUM_OFF  (WBF_OFF + WBF_SZF)
#define PSUM_SZF  ((size_t)NVT * (TM * BB))         // 384,000 f (tile-major)
#define NEED_F    (PSUM_OFF + PSUM_SZF)

__device__ __forceinline__ float sigf(float x) { return 1.f / (1.f + __expf(-x)); }

__device__ __forceinline__ unsigned short f2bf(float x) {
    unsigned bits = __float_as_uint(x);
    bits += 0x7FFFu + ((bits >> 16) & 1u);   // RNE
    return (unsigned short)(bits >> 16);
}

// ============ Kernel 1: prep = xih tiles + Whh cvt + Wread cvt (one launch) ============
__global__ void __launch_bounds__(256) k_prep(const int* __restrict__ src,
                                              const int* __restrict__ tgt,
                                              const float* __restrict__ emb,
                                              const float* __restrict__ Wih,
                                              const float* __restrict__ bih,
                                              const float* __restrict__ bhh,
                                              const float* __restrict__ Whh,
                                              const float* __restrict__ Wread,
                                              float* __restrict__ xih,
                                              unsigned short* __restrict__ whhbf,
                                              unsigned short* __restrict__ wbf) {
    __shared__ float xs[16 * EE];   // 16 KB
    const int bid = blockIdx.x;
    const int tid = threadIdx.x;

    if (bid < NXIH) {
        const int tok0 = (bid >> 3) * 16;
        const int row0 = (bid & 7) * 256;
        for (int e = tid; e < 16 * EE; e += 256) {
            int tk = e >> 8, k = e & 255;
            int tau = tok0 + tk;
            int idx = (tau < SS * BB) ? src[tau] : tgt[tau - SS * BB];
            xs[tk * EE + k] = (idx == 0) ? 0.f : emb[(size_t)idx * EE + k];
        }
        __syncthreads();

        const int row = row0 + tid;
        const float bias = bih[row] + bhh[row];
        float acc[16];
#pragma unroll
        for (int r = 0; r < 16; ++r) acc[r] = bias;
        const float4* w4 = (const float4*)(Wih + (size_t)row * EE);
        for (int k4 = 0; k4 < EE / 4; ++k4) {
            float4 w = w4[k4];
#pragma unroll
            for (int r = 0; r < 16; ++r) {
                float4 x = *((const float4*)&xs[r * EE + k4 * 4]);
                acc[r] += w.x * x.x + w.y * x.y + w.z * x.z + w.w * x.w;
            }
        }
#pragma unroll
        for (int r = 0; r < 16; ++r)
            xih[(size_t)(tok0 + r) * G4 + row] = acc[r];
        return;
    }

    const float* srcp;
    unsigned short* dstp;
    size_t base;
    if (bid < NXIH + NCVTW) { srcp = Whh;   dstp = whhbf; base = (size_t)(bid - NXIH) * 2048; }
    else                    { srcp = Wread; dstp = wbf;   base = (size_t)(bid - NXIH - NCVTW) * 2048; }
    base += (size_t)tid * 8;
    float4 f0 = *(const float4*)(srcp + base);
    float4 f1 = *(const float4*)(srcp + base + 4);
    uint4 o;
    o.x = (unsigned)f2bf(f0.x) | ((unsigned)f2bf(f0.y) << 16);
    o.y = (unsigned)f2bf(f0.z) | ((unsigned)f2bf(f0.w) << 16);
    o.z = (unsigned)f2bf(f1.x) | ((unsigned)f2bf(f1.y) << 16);
    o.w = (unsigned)f2bf(f1.z) | ((unsigned)f2bf(f1.w) << 16);
    *(uint4*)(dstp + base) = o;
}

// ============ Kernel 2: LSTM scan — r11 structure, regular launch (r14-verified) ============
__global__ void __launch_bounds__(256, 1) k_lstm(const float* __restrict__ xih,
                                                 const unsigned short* __restrict__ whhbf,
                                                 float* __restrict__ hall,
                                                 unsigned short* __restrict__ hbf,
                                                 unsigned short* __restrict__ abf,
                                                 unsigned* __restrict__ flags) {
    __shared__ short lA[65536];   // 131072 B static
    const int tid = threadIdx.x;
    const int wv  = tid >> 6;
    const int l   = tid & 63;
    const int b16 = l & 15;
    const int kg  = l >> 4;
    const int bb  = b16 & 7;
    const int bx  = blockIdx.x;
    const int I0  = bx * 32 + wv * 8;

    const int j = b16;
    const unsigned short* a0p = whhbf + ((size_t)((j >> 3) * HH + I0 + (j & 7))) * HH + kg * 8;
    const unsigned short* a1p = whhbf + ((size_t)((2 + (j >> 3)) * HH + I0 + (j & 7))) * HH + kg * 8;
    short* lA0 = lA + (((size_t)wv * 2 + 0) * 16 * 64 + l) * 8;
    short* lA1 = lA + (((size_t)wv * 2 + 1) * 16 * 64 + l) * 8;
#pragma unroll
    for (int ks = 0; ks < 16; ++ks) {
        *(short8*)(lA0 + ks * 512) = *(const short8*)(a0p + ks * 32);
        *(short8*)(lA1 + ks * 512) = *(const short8*)(a1p + ks * 32);
    }
    __syncthreads();

    const int xgate0 = (kg >> 1);
    const int xgate1 = 2 + (kg >> 1);
    const int xi     = I0 + (kg & 1) * 4;

    float c0[4] = {0.f, 0.f, 0.f, 0.f};
    union fragu { uint32x4 u4; short8 s; };

    for (int t = 0; t < NTOK; ++t) {
        const float* xb = xih + ((size_t)t * BB + bb) * G4;
        float4 x0 = *(const float4*)(xb + xgate0 * HH + xi);
        float4 x1 = *(const float4*)(xb + xgate1 * HH + xi);

        fragu Bf[16];
        if (t > 0) {
            if (l < 16) {
                while (__hip_atomic_load(&flags[(size_t)l * 16], __ATOMIC_RELAXED,
                                         __HIP_MEMORY_SCOPE_AGENT) < (unsigned)t) {}
            }
            const unsigned short* hsrc =
                hbf + ((t - 1) & 1) * (BB * HH) + (size_t)bb * HH + kg * 8;
#pragma unroll
            for (int ks = 0; ks < 16; ++ks)
                asm volatile("global_load_dwordx4 %0, %1, off sc0 sc1"
                             : "=v"(Bf[ks].u4) : "v"(hsrc + ks * 32) : "memory");
            asm volatile("s_waitcnt vmcnt(0)" ::: "memory");
            __builtin_amdgcn_sched_barrier(0);
        }

        f32x4 acc0 = {x0.x, x0.y, x0.z, x0.w};
        f32x4 acc1 = {x1.x, x1.y, x1.z, x1.w};
        if (t > 0) {
#pragma unroll
            for (int ks = 0; ks < 16; ++ks) {
                short8 a0 = *(const short8*)(lA0 + ks * 512);
                short8 a1 = *(const short8*)(lA1 + ks * 512);
                acc0 = __builtin_amdgcn_mfma_f32_16x16x32_bf16(a0, Bf[ks].s, acc0, 0, 0, 0);
                acc1 = __builtin_amdgcn_mfma_f32_16x16x32_bf16(a1, Bf[ks].s, acc1, 0, 0, 0);
            }
        }

        float hreg[4];
#pragma unroll
        for (int r = 0; r < 4; ++r) {
            float gf = __shfl_down(acc0[r], 32, 64);
            float go = __shfl_down(acc1[r], 32, 64);
            float is = sigf(acc0[r]);
            float fs = sigf(gf);
            float gv = tanhf(acc1[r]);
            float os = sigf(go);
            c0[r] = fs * c0[r] + is * gv;
            hreg[r] = os * tanhf(c0[r]);
        }

        if (l < 32 && b16 < BB) {
            const int ib = I0 + kg * 4;
            *(float4*)(hall + ((size_t)t * BB + b16) * HH + ib) =
                make_float4(hreg[0], hreg[1], hreg[2], hreg[3]);
            u64 pk = (u64)f2bf(hreg[0]) | ((u64)f2bf(hreg[1]) << 16) |
                     ((u64)f2bf(hreg[2]) << 32) | ((u64)f2bf(hreg[3]) << 48);
            if (t >= SS)
                *(u64*)(abf + ((size_t)(t - SS) * BB + b16) * HH + ib) = pk;
            if (t < NTOK - 1) {
                unsigned short* hdst = hbf + (t & 1) * (BB * HH) + (size_t)b16 * HH + ib;
                asm volatile("global_store_dwordx2 %0, %1, off sc0 sc1"
                             :: "v"(hdst), "v"(pk) : "memory");
            }
        }

        if (t < NTOK - 1) {
            asm volatile("s_waitcnt vmcnt(0)" ::: "memory");
            __syncthreads();
            if (tid == 0)
                __hip_atomic_store(&flags[(size_t)bx * 16], (unsigned)(t + 1),
                                   __ATOMIC_RELAXED, __HIP_MEMORY_SCOPE_AGENT);
        }
    }
}

// ============ Kernel 3: Q = tanh(Hdec @ W_att^T). grid TM, block 256 ============
__global__ void __launch_bounds__(256) k_q(const float* __restrict__ hall,
                                           const float* __restrict__ Watt,
                                           float* __restrict__ q) {
    __shared__ float hb[8 * 516];
    const int t = blockIdx.x, tid = threadIdx.x;
    const float* hdec = hall + (size_t)(SS + t) * (BB * HH);
    for (int e = tid; e < BB * HH; e += 256)
        hb[(e >> 9) * 516 + (e & 511)] = hdec[e];
    __syncthreads();

    for (int oi = tid; oi < BB * HH; oi += 256) {
        int b = oi & 7, ii = oi >> 3;
        const float4* w4 = (const float4*)(Watt + (size_t)ii * HH);
        const float4* h4 = (const float4*)(hb + b * 516);
        float acc = 0.f;
        for (int k4 = 0; k4 < HH / 4; ++k4) {
            float4 w = w4[k4], h = h4[k4];
            acc += w.x * h.x + w.y * h.y + w.z * h.z + w.w * h.w;
        }
        q[(size_t)(t * BB + b) * HH + ii] = tanhf(acc);
    }
}

// ============ Kernel 4: attention scores + softmax + pointer gather ============
__global__ void __launch_bounds__(256) k_att(const float* __restrict__ hall,
                                             const float* __restrict__ q,
                                             const float* __restrict__ sent,
                                             const int* __restrict__ src,
                                             const int* __restrict__ tgt,
                                             float* __restrict__ pptr,
                                             float* __restrict__ asent) {
    __shared__ float qs[HH];
    __shared__ float av[256];
    __shared__ float red[256];
    const int t = blockIdx.x, b = blockIdx.y, tid = threadIdx.x;

    for (int e = tid; e < HH; e += 256) qs[e] = q[(size_t)(t * BB + b) * HH + e];
    __syncthreads();

    const int j = tid;
    float acc = NEGF;
    if (j < SS + TM + 1) {
        bool valid = (j < SS + t + 1) || (j == SS + TM);
        if (valid) {
            const float* vptr = (j < SS + TM) ? (hall + (size_t)(j * BB + b) * HH) : sent;
            const float4* v4 = (const float4*)vptr;
            const float4* q4 = (const float4*)qs;
            float a = 0.f;
            for (int k4 = 0; k4 < HH / 4; ++k4) {
                float4 v = v4[k4], qq = q4[k4];
                a += v.x * qq.x + v.y * qq.y + v.z * qq.z + v.w * qq.w;
            }
            acc = a;
        }
    }
    red[tid] = acc;
    __syncthreads();
    for (int s2 = 128; s2 > 0; s2 >>= 1) {
        if (tid < s2) red[tid] = fmaxf(red[tid], red[tid + s2]);
        __syncthreads();
    }
    float m = red[0];
    __syncthreads();
    float e = __expf(acc - m);
    red[tid] = e;
    __syncthreads();
    for (int s2 = 128; s2 > 0; s2 >>= 1) {
        if (tid < s2) red[tid] += red[tid + s2];
        __syncthreads();
    }
    float denom = red[0];
    __syncthreads();
    float a = e / denom;
    av[tid] = a;
    __syncthreads();

    const int vs = tgt[(t + 1) * BB + b];
    float contrib = 0.f;
    if (j < SS) {
        if (src[j * BB + b] == vs) contrib += av[j];        // a_src
        if (tgt[j * BB + b] == vs) contrib += av[SS + j];   // a_tgt
    }
    red[tid] = contrib;
    __syncthreads();
    for (int s2 = 128; s2 > 0; s2 >>= 1) {
        if (tid < s2) red[tid] += red[tid + s2];
        __syncthreads();
    }
    if (tid == 0) {
        pptr[t * BB + b]  = red[0];
        asent[t * BB + b] = av[SS + TM];
    }
}

// ============ Kernel 5: vocab stats via bf16 MFMA, B in LDS, PARTIAL-SUM stores ============
// 500 blocks x 64 cols. Replaces 384K serialized atomicAdds (500/row onto 48 cache
// lines) with plain per-tile partial stores psum[tile][row]; k_final reduces them
// coalesced. Zero atomics in the hot path (Guideline 12, two-stage).
__global__ void __launch_bounds__(256) k_vocab_mfma(const unsigned short* __restrict__ Abf,
                                                    const unsigned short* __restrict__ Wbf,
                                                    const int* __restrict__ tgt,
                                                    float* __restrict__ psum,
                                                    float* __restrict__ lstar) {
    __shared__ short lB[32768];   // 64 KB
    const int tid  = threadIdx.x;
    const int lane = tid & 63;
    const int r16  = lane & 15;
    const int kg   = lane >> 4;
    const int n0   = blockIdx.x * 64;

    for (int s = tid; s < 4096; s += 256) {
        const int slot = s >> 6;
        const int cb = slot >> 4, ks = slot & 15;
        const int ll = s & 63;
        const int rr = ll & 15, kk = ll >> 4;
        *(short8*)(lB + (size_t)s * 8) =
            *(const short8*)(Wbf + (size_t)(n0 + cb * 16 + rr) * HH + ks * 32 + kk * 8);
    }
    __syncthreads();

    const short* lBme = lB + (size_t)lane * 8;

    for (int pass = 0; pass < 12; ++pass) {
        const int row0 = pass * 64 + (tid >> 6) * 16;
        const unsigned short* arow = Abf + (size_t)(row0 + r16) * HH + kg * 8;

        f32x4 acc0 = {0.f,0.f,0.f,0.f}, acc1 = acc0, acc2 = acc0, acc3 = acc0;
#pragma unroll
        for (int ks = 0; ks < 16; ++ks) {
            short8 a = *(const short8*)(arow + ks * 32);
            acc0 = __builtin_amdgcn_mfma_f32_16x16x32_bf16(a, *(const short8*)(lBme + (size_t)(0 * 16 + ks) * 512), acc0, 0, 0, 0);
            acc1 = __builtin_amdgcn_mfma_f32_16x16x32_bf16(a, *(const short8*)(lBme + (size_t)(1 * 16 + ks) * 512), acc1, 0, 0, 0);
            acc2 = __builtin_amdgcn_mfma_f32_16x16x32_bf16(a, *(const short8*)(lBme + (size_t)(2 * 16 + ks) * 512), acc2, 0, 0, 0);
            acc3 = __builtin_amdgcn_mfma_f32_16x16x32_bf16(a, *(const short8*)(lBme + (size_t)(3 * 16 + ks) * 512), acc3, 0, 0, 0);
        }

#pragma unroll
        for (int reg = 0; reg < 4; ++reg) {
            const int rowg = row0 + 4 * kg + reg;
            const int vs = tgt[BB + rowg];
            int cg;
            cg = n0 +  0 + r16; if (cg == vs) lstar[rowg] = acc0[reg];
            cg = n0 + 16 + r16; if (cg == vs) lstar[rowg] = acc1[reg];
            cg = n0 + 32 + r16; if (cg == vs) lstar[rowg] = acc2[reg];
            cg = n0 + 48 + r16; if (cg == vs) lstar[rowg] = acc3[reg];

            float v = __expf(acc0[reg]) + __expf(acc1[reg]) +
                      __expf(acc2[reg]) + __expf(acc3[reg]);
            v += __shfl_xor(v, 1, 64);
            v += __shfl_xor(v, 2, 64);
            v += __shfl_xor(v, 4, 64);
            v += __shfl_xor(v, 8, 64);
            if (r16 == 0) psum[(size_t)blockIdx.x * (TM * BB) + rowg] = v;   // plain store
        }
    }
}

// ============ Kernel 5-fallback: f32 vocab stats (atomics into ssum) ============
__global__ void __launch_bounds__(256) k_vocab_f32(const float* __restrict__ hall,
                                                   const float* __restrict__ Wread,
                                                   const int* __restrict__ tgt,
                                                   float* __restrict__ ssum,
                                                   float* __restrict__ lstar) {
    __shared__ float hs[32 * HH];   // 64 KB
    const int tid = threadIdx.x;
    const int v0 = blockIdx.x * 512 + tid * 2;
    const int v1 = v0 + 1;
    const bool g0 = v0 < VV, g1 = v1 < VV;
    const float4* w40 = (const float4*)(Wread + (size_t)(g0 ? v0 : 0) * HH);
    const float4* w41 = (const float4*)(Wread + (size_t)(g1 ? v1 : 0) * HH);
    const int rbase0 = blockIdx.y * 128;

    for (int ch = 0; ch < 4; ++ch) {
        const int rbase = rbase0 + ch * 32;
        const float4* sp4 = (const float4*)(hall + ((size_t)SS * BB + rbase) * HH);
        float4* hs4 = (float4*)hs;
        for (int e = tid; e < 32 * HH / 4; e += 256) hs4[e] = sp4[e];
        __syncthreads();

        float acc0[32], acc1[32];
#pragma unroll
        for (int r = 0; r < 32; ++r) { acc0[r] = 0.f; acc1[r] = 0.f; }

        for (int k4 = 0; k4 < HH / 4; ++k4) {
            float4 w0 = w40[k4];
            float4 w1 = w41[k4];
#pragma unroll
            for (int r = 0; r < 32; ++r) {
                float4 h = *((const float4*)(hs + r * HH + k4 * 4));
                acc0[r] += w0.x * h.x + w0.y * h.y + w0.z * h.z + w0.w * h.w;
                acc1[r] += w1.x * h.x + w1.y * h.y + w1.z * h.z + w1.w * h.w;
            }
        }

#pragma unroll
        for (int r = 0; r < 32; ++r) {
            const int row = rbase + r;
            float val = 0.f;
            if (g0) val += __expf(acc0[r]);
            if (g1) val += __expf(acc1[r]);
#pragma unroll
            for (int d = 32; d > 0; d >>= 1) val += __shfl_xor(val, d, 64);
            if ((tid & 63) == 0) atomicAdd(&ssum[row], val);
            const int vs = tgt[row + BB];
            if (g0 && v0 == vs) lstar[row] = acc0[r];
            else if (g1 && v1 == vs) lstar[row] = acc1[r];
        }
        __syncthreads();
    }
}

// ============ Kernel 6: psum reduce + gold log-likelihoods + per-batch sums ============
__global__ void __launch_bounds__(768) k_final(const float* __restrict__ pptr,
                                               const float* __restrict__ asent,
                                               const float* __restrict__ ssum,
                                               const float* __restrict__ lstar,
                                               const float* __restrict__ psum,
                                               const int use_psum,
                                               const int* __restrict__ tgt,
                                               float* __restrict__ out) {
    __shared__ float g[TM * BB], gp[TM * BB];
    const int tid = threadIdx.x;          // = t*8+b
    float ss;
    if (use_psum) {
        // coalesced: iteration-major, threads read consecutive addresses
        float s0 = 0.f, s1 = 0.f, s2 = 0.f, s3 = 0.f;
        for (int q = 0; q < NVT; q += 4) {
            s0 += psum[(size_t)(q + 0) * (TM * BB) + tid];
            s1 += psum[(size_t)(q + 1) * (TM * BB) + tid];
            s2 += psum[(size_t)(q + 2) * (TM * BB) + tid];
            s3 += psum[(size_t)(q + 3) * (TM * BB) + tid];
        }
        ss = (s0 + s1) + (s2 + s3);
    } else {
        ss = ssum[tid];
    }

    const int vs = tgt[tid + BB];
    const float pv = __expf(lstar[tid]) / ss;
    const float ps = pptr[tid];
    const float as = asent[tid];
    if (vs != 0) {
        g[tid]  = logf(ps + pv * as);
        gp[tid] = logf(ps + as);
    } else {
        g[tid] = 0.f; gp[tid] = 0.f;
    }
    __syncthreads();
    if (tid < BB) {
        float su1 = 0.f, su2 = 0.f;
        for (int t = 0; t < TM; ++t) { su1 += g[t * BB + tid]; su2 += gp[t * BB + tid]; }
        out[tid] = su1;
        out[BB + tid] = su2;
    }
}

extern "C" void kernel_launch(void* const* d_in, const int* in_sizes, int n_in,
                              void* d_out, int out_size, void* d_ws, size_t ws_size,
                              hipStream_t stream) {
    (void)in_sizes; (void)n_in; (void)out_size;
    const int*   src   = (const int*)d_in[0];
    const int*   tgt   = (const int*)d_in[1];
    const float* emb   = (const float*)d_in[2];
    const float* Wih   = (const float*)d_in[3];
    const float* Whh   = (const float*)d_in[4];
    const float* bih   = (const float*)d_in[5];
    const float* bhh   = (const float*)d_in[6];
    const float* Watt  = (const float*)d_in[7];
    const float* sent  = (const float*)d_in[8];
    const float* Wread = (const float*)d_in[9];
    float* ws  = (float*)d_ws;
    float* out = (float*)d_out;

    const bool use_mfma_vocab = ws_size >= NEED_F * sizeof(float);

    // zero SSUM + LSTAR + FLAGS (contiguous: 768+768+1024)
    (void)hipMemsetAsync((void*)(ws + SSUM_OFF), 0, (size_t)2560 * sizeof(float), stream);

    k_prep<<<dim3(NPREP), 256, 0, stream>>>(
        src, tgt, emb, Wih, bih, bhh, Whh, Wread,
        ws + XIH_OFF, (unsigned short*)(ws + WHHBF_OFF), (unsigned short*)(ws + WBF_OFF));

    k_lstm<<<dim3(LBLK), 256, 0, stream>>>(
        ws + XIH_OFF, (const unsigned short*)(ws + WHHBF_OFF), ws + HALL_OFF,
        (unsigned short*)(ws + HBF_OFF), (unsigned short*)(ws + ABF_OFF),
        (unsigned*)(ws + FLAG_OFF));

    k_q<<<dim3(TM), 256, 0, stream>>>(ws + HALL_OFF, Watt, ws + Q_OFF);

    k_att<<<dim3(TM, BB), 256, 0, stream>>>(ws + HALL_OFF, ws + Q_OFF, sent,
                                            src, tgt, ws + PPTR_OFF, ws + ASENT_OFF);

    if (use_mfma_vocab) {
        k_vocab_mfma<<<dim3(NVT), 256, 0, stream>>>(
            (const unsigned short*)(ws + ABF_OFF),
            (const unsigned short*)(ws + WBF_OFF),
            tgt, ws + PSUM_OFF, ws + LSTAR_OFF);
    } else {
        k_vocab_f32<<<dim3(63, 6), 256, 0, stream>>>(ws + HALL_OFF, Wread, tgt,
                                                     ws + SSUM_OFF, ws + LSTAR_OFF);
    }

    k_final<<<dim3(1), dim3(TM * BB), 0, stream>>>(ws + PPTR_OFF, ws + ASENT_OFF,
                                                   ws + SSUM_OFF, ws + LSTAR_OFF,
                                                   ws + PSUM_OFF, use_mfma_vocab ? 1 : 0,
                                                   tgt, out);
}